// Round 3
// baseline (609.470 us; speedup 1.0000x reference)
//
#include <hip/hip_runtime.h>
#include <hip/hip_bf16.h>
#include <cstdint>

typedef __bf16 bf16;
typedef __attribute__((ext_vector_type(8))) __bf16 bf16x8;
typedef __attribute__((ext_vector_type(4))) float f32x4;

__device__ __forceinline__ float fast_rcp(float x) { return __builtin_amdgcn_rcpf(x); }
__device__ __forceinline__ float silu_f(float x) { return x * fast_rcp(1.f + __expf(-x)); }
__device__ __forceinline__ bf16x8 cvt8(float4 a, float4 b) {
  bf16x8 o;
  o[0]=(bf16)a.x; o[1]=(bf16)a.y; o[2]=(bf16)a.z; o[3]=(bf16)a.w;
  o[4]=(bf16)b.x; o[5]=(bf16)b.y; o[6]=(bf16)b.z; o[7]=(bf16)b.w;
  return o;
}

// ---------------- ws layout (byte offsets) ----------------
constexpr long O_W2P   = 0;         // 8192*8 bf16 = 131072 B (pair W2 frags)
constexpr long O_WDP   = 131072;    // 512*256 bf16 = 262144 B (stacked dp_w1)
constexpr long O_B512  = 393216;    // 512 f32 (bias for aiaj gemm)
constexpr long F_ZIN   = 395264;    // 512*192 f32
constexpr long F_G     = 788480;    // 256 f32
constexpr long F_H     = 789504;    // 512*256 f32
constexpr long F_QKV   = 1313792;   // 512*768 f32
constexpr long F_FF1   = 2886656;   // 512*1024 f32
constexpr long F_O     = 4983808;   // 512*256 f32
constexpr long F_T1    = 5508096;   // 512*256 f32
constexpr long F_AIAJ  = 6032384;   // 512*512 f32

// ---------------- prep: zin concat + W2 perm + dpw1 pack + gproj + bias512 ----------------
__global__ __launch_bounds__(256) void prep_kernel(
    const float* __restrict__ z, const int* __restrict__ at, const float* __restrict__ emb,
    const float* __restrict__ dpw2, const float* __restrict__ dpw1,
    const float* __restrict__ zg, const float* __restrict__ gw1, const float* __restrict__ gb1,
    const float* __restrict__ gw2, const float* __restrict__ gb2,
    const float* __restrict__ dpb1,
    float* __restrict__ zi, bf16* __restrict__ w2p, bf16* __restrict__ wdp,
    float* __restrict__ g, float* __restrict__ bias512)
{
  __shared__ float zs[128];
  __shared__ float ts[256];
  const int b = blockIdx.x, tid = threadIdx.x;
  if (b < 384) {                       // z_input concat
    int idx = b * 256 + tid;
    int n = idx / 192, c = idx - n * 192;
    zi[idx] = (c < 128) ? z[n * 128 + c] : emb[at[n] * 64 + (c - 128)];
  } else if (b < 416) {                // W2 -> B-frag-linear bf16
    int f = (b - 384) * 256 + tid;     // 8192 frags
    int l15 = f & 15, kq = (f >> 4) & 3, ks = (f >> 6) & 7, nt = f >> 9;
    int n = nt * 16 + l15, k0 = ks * 32 + kq * 8;
    float4 v0 = *(const float4*)&dpw2[n * 256 + k0];
    float4 v1 = *(const float4*)&dpw2[n * 256 + k0 + 4];
    *(bf16x8*)&w2p[(long)f * 8] = cvt8(v0, v1);
  } else if (b < 544) {                // stacked dp_w1 (512x256) bf16
    int v = (b - 416) * 256 + tid;     // 32768 vec4
    int r = v >> 6, c4 = (v & 63) << 2;
    long src = (r < 256) ? ((long)r * 512 + c4) : ((long)(r - 256) * 512 + 256 + c4);
    float4 f = *(const float4*)&dpw1[src];
    bf16* d = &wdp[r * 256 + c4];
    d[0]=(bf16)f.x; d[1]=(bf16)f.y; d[2]=(bf16)f.z; d[3]=(bf16)f.w;
  } else if (b == 544) {               // global MLP
    if (tid < 128) zs[tid] = zg[tid];
    __syncthreads();
    float s = gb1[tid];
    for (int k = 0; k < 128; ++k) s += zs[k] * gw1[tid * 128 + k];
    ts[tid] = silu_f(s);
    __syncthreads();
    float s2 = gb2[tid];
    for (int k = 0; k < 256; ++k) s2 += ts[k] * gw2[tid * 256 + k];
    g[tid] = s2;
  } else {                             // bias512 = [dpb1, 0]
    bias512[tid] = dpb1[tid];
    bias512[256 + tid] = 0.f;
  }
}

// ---------------- generic MFMA GEMM: C = act(A @ W^T + bias) (+R) ----------------
template<int ACT, typename WT>
__global__ __launch_bounds__(256) void gemm_kernel(
    const float* __restrict__ A, int lda,
    const WT* __restrict__ W, int ldw,
    const float* __restrict__ bias,
    const float* __restrict__ R, int ldr,
    float* __restrict__ C, int ldc, int K)
{
  const int m0 = blockIdx.x * 64, n0 = blockIdx.y * 64;
  __shared__ bf16 As[64][72];
  __shared__ bf16 Ws[64][72];
  const int tid = threadIdx.x;
  const int lane = tid & 63, wid = tid >> 6;
  const int wm = (wid & 1) * 32, wn = (wid >> 1) * 32;
  const int rr = lane & 15, kg = (lane >> 4) << 3;
  f32x4 acc[2][2] = {};
  for (int k0 = 0; k0 < K; k0 += 64) {
#pragma unroll
    for (int r = 0; r < 4; ++r) {
      int lin = tid + r * 256;
      int row = lin >> 4, kc = (lin & 15) << 2;
      {
        const float* p = &A[(long)(m0 + row) * lda + k0 + kc];
        float4 v = *(const float4*)p;
        As[row][kc] = (bf16)v.x; As[row][kc + 1] = (bf16)v.y;
        As[row][kc + 2] = (bf16)v.z; As[row][kc + 3] = (bf16)v.w;
      }
      {
        const WT* p = &W[(long)(n0 + row) * ldw + k0 + kc];
        if constexpr (sizeof(WT) == 4) {
          float4 v = *(const float4*)p;
          Ws[row][kc] = (bf16)v.x; Ws[row][kc + 1] = (bf16)v.y;
          Ws[row][kc + 2] = (bf16)v.z; Ws[row][kc + 3] = (bf16)v.w;
        } else {
          *(uint2*)&Ws[row][kc] = *(const uint2*)p;
        }
      }
    }
    __syncthreads();
#pragma unroll
    for (int ks = 0; ks < 2; ++ks) {
      const int kk = ks * 32 + kg;
      bf16x8 a0 = *(const bf16x8*)&As[wm + rr][kk];
      bf16x8 a1 = *(const bf16x8*)&As[wm + 16 + rr][kk];
      bf16x8 b0 = *(const bf16x8*)&Ws[wn + rr][kk];
      bf16x8 b1 = *(const bf16x8*)&Ws[wn + 16 + rr][kk];
      acc[0][0] = __builtin_amdgcn_mfma_f32_16x16x32_bf16(a0, b0, acc[0][0], 0, 0, 0);
      acc[0][1] = __builtin_amdgcn_mfma_f32_16x16x32_bf16(a0, b1, acc[0][1], 0, 0, 0);
      acc[1][0] = __builtin_amdgcn_mfma_f32_16x16x32_bf16(a1, b0, acc[1][0], 0, 0, 0);
      acc[1][1] = __builtin_amdgcn_mfma_f32_16x16x32_bf16(a1, b1, acc[1][1], 0, 0, 0);
    }
    __syncthreads();
  }
  const int rg = lane >> 4;
#pragma unroll
  for (int mi = 0; mi < 2; ++mi)
#pragma unroll
    for (int ni = 0; ni < 2; ++ni)
#pragma unroll
      for (int r = 0; r < 4; ++r) {
        int gm = m0 + wm + mi * 16 + rg * 4 + r;
        int gn = n0 + wn + ni * 16 + rr;
        float v = acc[mi][ni][r];
        if (bias) v += bias[gn];
        if (R) v += R[(long)gm * ldr + gn];
        if (ACT == 1) v = silu_f(v);
        else if (ACT == 2) v = fmaxf(v, 0.f);
        C[(long)gm * ldc + gn] = v;
      }
}

// ---------------- fused attention (exact softmax, per layer) ----------------
// grid (8 qtiles, 4 heads), 256 threads. Wave w owns q-rows w*16..w*16+15,
// all 512 keys. S in regs (32 f32x4), softmax in-lane+shfl, P -> per-wave LDS
// (A-frag layout), V transposed-staged in 128-key chunks, PV accumulates O.
__global__ __launch_bounds__(256) void attn_kernel(
    const float* __restrict__ qkv, float* __restrict__ o)
{
  __shared__ bf16 p_lds[4][8192];    // per wave: [(kk*16 + m)*8 + e], key = kk*8+e
  __shared__ bf16 vt_lds[8192];      // per chunk: [(kkl*64 + d)*8 + e]
  const int tid = threadIdx.x, lane = tid & 63, w = tid >> 6;
  const int l15 = lane & 15, kq = lane >> 4;
  const int q0 = blockIdx.x * 64, h = blockIdx.y;

  // Q A-frags (rows w*16+l15, d = ksq*32+kq*8)
  const float* qrow = qkv + (long)(q0 + w * 16 + l15) * 768 + h * 64 + kq * 8;
  bf16x8 qa[2];
#pragma unroll
  for (int ksq = 0; ksq < 2; ++ksq) {
    float4 f0 = *(const float4*)(qrow + ksq * 32);
    float4 f1 = *(const float4*)(qrow + ksq * 32 + 4);
    qa[ksq] = cvt8(f0, f1);
  }
  // S = Q @ K^T  (keys = nt*16+l15)
  f32x4 accS[32];
#pragma unroll
  for (int nt = 0; nt < 32; ++nt) accS[nt] = (f32x4){0.f, 0.f, 0.f, 0.f};
#pragma unroll
  for (int nt = 0; nt < 32; ++nt) {
    const float* krow = qkv + (long)(nt * 16 + l15) * 768 + 256 + h * 64 + kq * 8;
    float4 a0 = *(const float4*)(krow);
    float4 a1 = *(const float4*)(krow + 4);
    float4 b0 = *(const float4*)(krow + 32);
    float4 b1 = *(const float4*)(krow + 36);
    bf16x8 kb0 = cvt8(a0, a1), kb1 = cvt8(b0, b1);
    accS[nt] = __builtin_amdgcn_mfma_f32_16x16x32_bf16(qa[0], kb0, accS[nt], 0, 0, 0);
    accS[nt] = __builtin_amdgcn_mfma_f32_16x16x32_bf16(qa[1], kb1, accS[nt], 0, 0, 0);
  }
  // exact softmax per row (r): reduce over nt in-lane, then shfl over l15
#pragma unroll
  for (int r = 0; r < 4; ++r) {
    float mx = accS[0][r];
#pragma unroll
    for (int nt = 1; nt < 32; ++nt) mx = fmaxf(mx, accS[nt][r]);
    mx = fmaxf(mx, __shfl_xor(mx, 1)); mx = fmaxf(mx, __shfl_xor(mx, 2));
    mx = fmaxf(mx, __shfl_xor(mx, 4)); mx = fmaxf(mx, __shfl_xor(mx, 8));
    float s = 0.f;
#pragma unroll
    for (int nt = 0; nt < 32; ++nt) {
      float p = __expf((accS[nt][r] - mx) * 0.125f);
      accS[nt][r] = p; s += p;
    }
    s += __shfl_xor(s, 1); s += __shfl_xor(s, 2);
    s += __shfl_xor(s, 4); s += __shfl_xor(s, 8);
    float iv = fast_rcp(s);
#pragma unroll
    for (int nt = 0; nt < 32; ++nt) accS[nt][r] *= iv;
  }
  // write P (bf16) to per-wave LDS in A-frag layout
  bf16* pw = &p_lds[w][0];
  const int ehi = l15 >> 3, elo = l15 & 7;
#pragma unroll
  for (int nt = 0; nt < 32; ++nt)
#pragma unroll
    for (int r = 0; r < 4; ++r)
      pw[((nt * 2 + ehi) * 16 + kq * 4 + r) * 8 + elo] = (bf16)accS[nt][r];

  // PV over 4 chunks of 128 keys
  f32x4 accO[4] = {};
  const int vd = tid & 63, kgrp = tid >> 6;
  for (int kc = 0; kc < 4; ++kc) {
    __syncthreads();
#pragma unroll
    for (int it = 0; it < 4; ++it) {
      int kkl = kgrp * 4 + it;                      // 0..15
      const float* vp = qkv + (long)(kc * 128 + kkl * 8) * 768 + 512 + h * 64 + vd;
      bf16x8 vv;
#pragma unroll
      for (int e = 0; e < 8; ++e) vv[e] = (bf16)vp[e * 768];
      *(bf16x8*)&vt_lds[(kkl * 64 + vd) * 8] = vv;
    }
    __syncthreads();
#pragma unroll
    for (int ksq = 0; ksq < 4; ++ksq) {
      bf16x8 pa = *(const bf16x8*)&pw[((kc * 16 + ksq * 4 + kq) * 16 + l15) * 8];
#pragma unroll
      for (int ntd = 0; ntd < 4; ++ntd) {
        bf16x8 vb = *(const bf16x8*)&vt_lds[((ksq * 4 + kq) * 64 + ntd * 16 + l15) * 8];
        accO[ntd] = __builtin_amdgcn_mfma_f32_16x16x32_bf16(pa, vb, accO[ntd], 0, 0, 0);
      }
    }
  }
#pragma unroll
  for (int ntd = 0; ntd < 4; ++ntd)
#pragma unroll
    for (int r = 0; r < 4; ++r)
      o[(long)(q0 + w * 16 + kq * 4 + r) * 256 + h * 64 + ntd * 16 + l15] = accO[ntd][r];
}

// ---------------- GEMM + bias + residual + LayerNorm fused ----------------
// grid(8): 64 rows x full 256 cols. Wave w -> col slice w*64. LN stats from
// accumulator registers (shfl over l15 + LDS cross-wave), no T materialization.
template<int KSTEPS>
__global__ __launch_bounds__(256) void gemmln_kernel(
    const float* __restrict__ A, int lda,
    const float* __restrict__ W, int ldw,
    const float* __restrict__ bias, const float* __restrict__ R,
    const float* __restrict__ sc, const float* __restrict__ bi,
    float* __restrict__ Y)
{
  __shared__ bf16 As[64][72];
  __shared__ float pstat[64][4][2];
  __shared__ float mstat[64][2];
  const int tid = threadIdx.x, lane = tid & 63, w = tid >> 6;
  const int l15 = lane & 15, kq = lane >> 4;
  const int m0 = blockIdx.x * 64;
  f32x4 acc[4][4] = {};
  for (int ki = 0; ki < KSTEPS; ++ki) {
    const int k0 = ki * 64;
#pragma unroll
    for (int r = 0; r < 4; ++r) {
      int lin = tid + r * 256;
      int row = lin >> 4, kc = (lin & 15) << 2;
      float4 v = *(const float4*)&A[(long)(m0 + row) * lda + k0 + kc];
      As[row][kc] = (bf16)v.x; As[row][kc + 1] = (bf16)v.y;
      As[row][kc + 2] = (bf16)v.z; As[row][kc + 3] = (bf16)v.w;
    }
    __syncthreads();
#pragma unroll
    for (int ks = 0; ks < 2; ++ks) {
#pragma unroll
      for (int nt = 0; nt < 4; ++nt) {
        const float* wp = &W[(long)(w * 64 + nt * 16 + l15) * ldw + k0 + ks * 32 + kq * 8];
        float4 f0 = *(const float4*)wp;
        float4 f1 = *(const float4*)(wp + 4);
        bf16x8 kb = cvt8(f0, f1);
#pragma unroll
        for (int mt = 0; mt < 4; ++mt) {
          bf16x8 af = *(const bf16x8*)&As[mt * 16 + l15][ks * 32 + kq * 8];
          acc[mt][nt] = __builtin_amdgcn_mfma_f32_16x16x32_bf16(af, kb, acc[mt][nt], 0, 0, 0);
        }
      }
    }
    __syncthreads();
  }
  float bv[4], scv[4], biv[4];
#pragma unroll
  for (int nt = 0; nt < 4; ++nt) {
    int col = w * 64 + nt * 16 + l15;
    bv[nt] = bias[col]; scv[nt] = sc[col]; biv[nt] = bi[col];
  }
#pragma unroll
  for (int mt = 0; mt < 4; ++mt)
#pragma unroll
    for (int r = 0; r < 4; ++r) {
      int gm = m0 + mt * 16 + kq * 4 + r;
      float s = 0.f, sq = 0.f;
#pragma unroll
      for (int nt = 0; nt < 4; ++nt) {
        float u = acc[mt][nt][r] + bv[nt] + R[(long)gm * 256 + w * 64 + nt * 16 + l15];
        acc[mt][nt][r] = u;
        s += u; sq += u * u;
      }
      s += __shfl_xor(s, 1); sq += __shfl_xor(sq, 1);
      s += __shfl_xor(s, 2); sq += __shfl_xor(sq, 2);
      s += __shfl_xor(s, 4); sq += __shfl_xor(sq, 4);
      s += __shfl_xor(s, 8); sq += __shfl_xor(sq, 8);
      if (l15 == 0) {
        pstat[mt * 16 + kq * 4 + r][w][0] = s;
        pstat[mt * 16 + kq * 4 + r][w][1] = sq;
      }
    }
  __syncthreads();
  if (tid < 64) {
    float s  = pstat[tid][0][0] + pstat[tid][1][0] + pstat[tid][2][0] + pstat[tid][3][0];
    float sq = pstat[tid][0][1] + pstat[tid][1][1] + pstat[tid][2][1] + pstat[tid][3][1];
    float mean = s * (1.f / 256.f);
    float var = sq * (1.f / 256.f) - mean * mean;
    mstat[tid][0] = mean;
    mstat[tid][1] = rsqrtf(var + 1e-5f);
  }
  __syncthreads();
#pragma unroll
  for (int mt = 0; mt < 4; ++mt)
#pragma unroll
    for (int r = 0; r < 4; ++r) {
      int m = mt * 16 + kq * 4 + r, gm = m0 + m;
      float mean = mstat[m][0], rstd = mstat[m][1];
#pragma unroll
      for (int nt = 0; nt < 4; ++nt) {
        int col = w * 64 + nt * 16 + l15;
        Y[(long)gm * 256 + col] = (acc[mt][nt][r] - mean) * rstd * scv[nt] + biv[nt];
      }
    }
}

// ---------------- fused pair/dist kernel (fast silu, grid 1024) ----------------
__global__ __launch_bounds__(256, 3) void pair2_kernel(
    const float* __restrict__ ai, const float* __restrict__ aj,
    const bf16* __restrict__ W2P, const float* __restrict__ b2g,
    const float* __restrict__ w3g, const float* __restrict__ b3p,
    float* __restrict__ dout)
{
  __shared__ float ai_s[256];
  __shared__ bf16  t_s[64 * 256];     // (kk*64 + p)*8 + e
  __shared__ float part[64][4];
  const int tid = threadIdx.x, lane = tid & 63, w = tid >> 6;
  const int l15 = lane & 15, kq = lane >> 4;
  const int i = blockIdx.x >> 1, half = blockIdx.x & 1;
  const float b3v = b3p[0];

  ai_s[tid] = ai[(long)i * 512 + tid];

  bf16x8 w2r[4][8];
  float b2v[4], w3v[4];
#pragma unroll
  for (int nt = 0; nt < 4; ++nt) {
    int ntg = w * 4 + nt;
#pragma unroll
    for (int ks = 0; ks < 8; ++ks)
      w2r[nt][ks] = *(const bf16x8*)&W2P[(long)((((ntg * 8 + ks) * 4 + kq) * 16) + l15) * 8];
    b2v[nt] = b2g[ntg * 16 + l15];
    w3v[nt] = w3g[ntg * 16 + l15];
  }
  __syncthreads();

  for (int jc = half * 4; jc < half * 4 + 4; ++jc) {
    const int j0 = jc * 64;
    const float* ajp = aj + (long)(j0 + lane) * 512;
#pragma unroll
    for (int r = 0; r < 8; ++r) {
      int kk = w + 4 * r;
      float4 a0 = *(const float4*)(ajp + kk * 8);
      float4 a1 = *(const float4*)(ajp + kk * 8 + 4);
      const float* aip = ai_s + kk * 8;
      bf16x8 tv;
      tv[0] = (bf16)silu_f(a0.x + aip[0]); tv[1] = (bf16)silu_f(a0.y + aip[1]);
      tv[2] = (bf16)silu_f(a0.z + aip[2]); tv[3] = (bf16)silu_f(a0.w + aip[3]);
      tv[4] = (bf16)silu_f(a1.x + aip[4]); tv[5] = (bf16)silu_f(a1.y + aip[5]);
      tv[6] = (bf16)silu_f(a1.z + aip[6]); tv[7] = (bf16)silu_f(a1.w + aip[7]);
      *(bf16x8*)&t_s[(kk * 64 + lane) * 8] = tv;
    }
    __syncthreads();   // t ready

    f32x4 acc[4][4] = {};
#pragma unroll
    for (int ks = 0; ks < 8; ++ks) {
      bf16x8 af[4];
#pragma unroll
      for (int Mt = 0; Mt < 4; ++Mt)
        af[Mt] = *(const bf16x8*)&t_s[((ks * 4 + kq) * 64 + Mt * 16 + l15) * 8];
#pragma unroll
      for (int nt = 0; nt < 4; ++nt)
#pragma unroll
        for (int Mt = 0; Mt < 4; ++Mt)
          acc[Mt][nt] = __builtin_amdgcn_mfma_f32_16x16x32_bf16(af[Mt], w2r[nt][ks], acc[Mt][nt], 0, 0, 0);
    }

#pragma unroll
    for (int Mt = 0; Mt < 4; ++Mt)
#pragma unroll
      for (int r = 0; r < 4; ++r) {
        float s = silu_f(acc[Mt][0][r] + b2v[0]) * w3v[0]
                + silu_f(acc[Mt][1][r] + b2v[1]) * w3v[1]
                + silu_f(acc[Mt][2][r] + b2v[2]) * w3v[2]
                + silu_f(acc[Mt][3][r] + b2v[3]) * w3v[3];
        s += __shfl_xor(s, 1); s += __shfl_xor(s, 2);
        s += __shfl_xor(s, 4); s += __shfl_xor(s, 8);
        if (l15 == 0) part[Mt * 16 + kq * 4 + r][w] = s;
      }
    __syncthreads();   // part ready
    if (tid < 64) {
      float s = part[tid][0] + part[tid][1] + part[tid][2] + part[tid][3] + b3v;
      float dd = fmaxf(s, 0.f) + log1pf(__expf(-fabsf(s)));
      dout[(long)i * 512 + j0 + tid] = dd;
    }
    __syncthreads();   // reuse t_s / part next iter
  }
}

// ---------------- symmetrize dist in place ----------------
__global__ __launch_bounds__(256) void sym_kernel(float* __restrict__ dist)
{
  int idx = blockIdx.x * 256 + threadIdx.x;
  int i = idx >> 9, j = idx & 511;
  if (i < j) {
    float a = dist[idx];
    float b = dist[(long)j * 512 + i];
    float m = 0.5f * (a + b);
    dist[idx] = m;
    dist[(long)j * 512 + i] = m;
  }
}

// ---------------- coordinate head final 256->3 ----------------
__global__ __launch_bounds__(256) void coord_kernel(
    const float* __restrict__ ct, const float* __restrict__ w2,
    const float* __restrict__ b2, float* __restrict__ out)
{
  int t = blockIdx.x * 256 + threadIdx.x;
  if (t >= 1536) return;
  int row = t / 3, c = t - row * 3;
  float s = b2[c];
  const float* a = &ct[(long)row * 256];
  const float* wp = &w2[c * 256];
  for (int k = 0; k < 256; ++k) s += a[k] * wp[k];
  out[t] = s;
}

extern "C" void kernel_launch(void* const* d_in, const int* in_sizes, int n_in,
                              void* d_out, int out_size, void* d_ws, size_t ws_size,
                              hipStream_t stream) {
  const float* z        = (const float*)d_in[0];
  const float* z_global = (const float*)d_in[1];
  const int*   atom_t   = (const int*)d_in[2];
  const float* emb      = (const float*)d_in[3];
  const float* ip_w1 = (const float*)d_in[4];  const float* ip_b1 = (const float*)d_in[5];
  const float* ip_w2 = (const float*)d_in[6];  const float* ip_b2 = (const float*)d_in[7];
  const float* gp_w1 = (const float*)d_in[8];  const float* gp_b1 = (const float*)d_in[9];
  const float* gp_w2 = (const float*)d_in[10]; const float* gp_b2 = (const float*)d_in[11];
  const float* wqkv  = (const float*)d_in[12]; const float* bqkv  = (const float*)d_in[13];
  const float* wo    = (const float*)d_in[14]; const float* bo    = (const float*)d_in[15];
  const float* ln1s  = (const float*)d_in[16]; const float* ln1b  = (const float*)d_in[17];
  const float* w1    = (const float*)d_in[18]; const float* b1    = (const float*)d_in[19];
  const float* w2    = (const float*)d_in[20]; const float* b2    = (const float*)d_in[21];
  const float* ln2s  = (const float*)d_in[22]; const float* ln2b  = (const float*)d_in[23];
  const float* dpw1  = (const float*)d_in[24]; const float* dpb1  = (const float*)d_in[25];
  const float* dpw2  = (const float*)d_in[26]; const float* dpb2  = (const float*)d_in[27];
  const float* dpw3  = (const float*)d_in[28]; const float* dpb3  = (const float*)d_in[29];
  const float* cpw1  = (const float*)d_in[30]; const float* cpb1  = (const float*)d_in[31];
  const float* cpw2  = (const float*)d_in[32]; const float* cpb2  = (const float*)d_in[33];

  char* ws = (char*)d_ws;
  bf16*  W2P  = (bf16*)(ws + O_W2P);
  bf16*  WDP  = (bf16*)(ws + O_WDP);
  float* b512 = (float*)(ws + O_B512);
  float* zin  = (float*)(ws + F_ZIN);
  float* g    = (float*)(ws + F_G);
  float* h    = (float*)(ws + F_H);
  float* qkv  = (float*)(ws + F_QKV);
  float* ff1  = (float*)(ws + F_FF1);
  float* o    = (float*)(ws + F_O);
  float* t1   = (float*)(ws + F_T1);
  float* aiaj = (float*)(ws + F_AIAJ);
  float* out  = (float*)d_out;
  float* xout = out;
  float* dist = out + 1536;

  prep_kernel<<<546, 256, 0, stream>>>(z, atom_t, emb, dpw2, dpw1,
      z_global, gp_w1, gp_b1, gp_w2, gp_b2, dpb1, zin, W2P, WDP, g, b512);

  gemm_kernel<1, float><<<dim3(8, 4), 256, 0, stream>>>(zin, 192, ip_w1, 192,
      ip_b1, nullptr, 0, t1, 256, 192);
  gemm_kernel<0, float><<<dim3(8, 4), 256, 0, stream>>>(t1, 256, ip_w2, 256,
      ip_b2, g, 0, h, 256, 256);

  for (int l = 0; l < 3; ++l) {
    gemm_kernel<0, float><<<dim3(8, 12), 256, 0, stream>>>(h, 256,
        wqkv + (long)l * 768 * 256, 256, bqkv + l * 768, nullptr, 0, qkv, 768, 256);
    attn_kernel<<<dim3(8, 4), 256, 0, stream>>>(qkv, o);
    gemmln_kernel<4><<<8, 256, 0, stream>>>(o, 256, wo + (long)l * 65536, 256,
        bo + l * 256, h, ln1s + l * 256, ln1b + l * 256, h);
    gemm_kernel<2, float><<<dim3(8, 16), 256, 0, stream>>>(h, 256,
        w1 + (long)l * 262144, 256, b1 + l * 1024, nullptr, 0, ff1, 1024, 256);
    gemmln_kernel<16><<<8, 256, 0, stream>>>(ff1, 1024, w2 + (long)l * 262144, 1024,
        b2 + l * 256, h, ln2s + l * 256, ln2b + l * 256, h);
  }

  // [ai | aj] = h @ [dpw1_lo ; dpw1_hi]^T + [b1 | 0]
  gemm_kernel<0, bf16><<<dim3(8, 8), 256, 0, stream>>>(h, 256, WDP, 256,
      b512, nullptr, 0, aiaj, 512, 256);
  pair2_kernel<<<1024, 256, 0, stream>>>(aiaj, aiaj + 256, W2P, dpb2, dpw3, dpb3, dist);
  sym_kernel<<<1024, 256, 0, stream>>>(dist);
  gemm_kernel<1, float><<<dim3(8, 4), 256, 0, stream>>>(h, 256, cpw1, 256,
      cpb1, nullptr, 0, t1, 256, 256);
  coord_kernel<<<6, 256, 0, stream>>>(t1, cpw2, cpb2, xout);
}

// Round 4
// 526.451 us; speedup vs baseline: 1.1577x; 1.1577x over previous
//
#include <hip/hip_runtime.h>
#include <hip/hip_bf16.h>
#include <cstdint>

typedef __bf16 bf16;
typedef __attribute__((ext_vector_type(8))) __bf16 bf16x8;
typedef __attribute__((ext_vector_type(4))) float f32x4;

__device__ __forceinline__ float fast_rcp(float x) { return __builtin_amdgcn_rcpf(x); }
__device__ __forceinline__ float silu_f(float x) { return x * fast_rcp(1.f + __expf(-x)); }
__device__ __forceinline__ bf16x8 cvt8(float4 a, float4 b) {
  bf16x8 o;
  o[0]=(bf16)a.x; o[1]=(bf16)a.y; o[2]=(bf16)a.z; o[3]=(bf16)a.w;
  o[4]=(bf16)b.x; o[5]=(bf16)b.y; o[6]=(bf16)b.z; o[7]=(bf16)b.w;
  return o;
}

// ---------------- ws layout (byte offsets) ----------------
constexpr long O_W2P   = 0;         // 8192*8 bf16 = 131072 B (pair W2 frags)
constexpr long O_WDP   = 131072;    // 512*256 bf16 = 262144 B (stacked dp_w1)
constexpr long O_B512  = 393216;    // 512 f32 (bias for aiaj gemm)
constexpr long F_ZIN   = 395264;    // 512*192 f32
constexpr long F_G     = 788480;    // 256 f32
constexpr long F_H     = 789504;    // 512*256 f32
constexpr long F_QKV   = 1313792;   // 512*768 f32
constexpr long F_FF1   = 2886656;   // 512*1024 f32
constexpr long F_O     = 4983808;   // 512*256 f32
constexpr long F_T1    = 5508096;   // 512*256 f32
constexpr long F_AIAJ  = 6032384;   // 512*512 f32

// ---------------- prep: zin concat + W2 perm + dpw1 pack + gproj + bias512 ----------------
__global__ __launch_bounds__(256) void prep_kernel(
    const float* __restrict__ z, const int* __restrict__ at, const float* __restrict__ emb,
    const float* __restrict__ dpw2, const float* __restrict__ dpw1,
    const float* __restrict__ zg, const float* __restrict__ gw1, const float* __restrict__ gb1,
    const float* __restrict__ gw2, const float* __restrict__ gb2,
    const float* __restrict__ dpb1,
    float* __restrict__ zi, bf16* __restrict__ w2p, bf16* __restrict__ wdp,
    float* __restrict__ g, float* __restrict__ bias512)
{
  __shared__ float zs[128];
  __shared__ float ts[256];
  const int b = blockIdx.x, tid = threadIdx.x;
  if (b < 384) {                       // z_input concat
    int idx = b * 256 + tid;
    int n = idx / 192, c = idx - n * 192;
    zi[idx] = (c < 128) ? z[n * 128 + c] : emb[at[n] * 64 + (c - 128)];
  } else if (b < 416) {                // W2 -> B-frag-linear bf16
    int f = (b - 384) * 256 + tid;     // 8192 frags
    int l15 = f & 15, kq = (f >> 4) & 3, ks = (f >> 6) & 7, nt = f >> 9;
    int n = nt * 16 + l15, k0 = ks * 32 + kq * 8;
    float4 v0 = *(const float4*)&dpw2[n * 256 + k0];
    float4 v1 = *(const float4*)&dpw2[n * 256 + k0 + 4];
    *(bf16x8*)&w2p[(long)f * 8] = cvt8(v0, v1);
  } else if (b < 544) {                // stacked dp_w1 (512x256) bf16
    int v = (b - 416) * 256 + tid;     // 32768 vec4
    int r = v >> 6, c4 = (v & 63) << 2;
    long src = (r < 256) ? ((long)r * 512 + c4) : ((long)(r - 256) * 512 + 256 + c4);
    float4 f = *(const float4*)&dpw1[src];
    bf16* d = &wdp[r * 256 + c4];
    d[0]=(bf16)f.x; d[1]=(bf16)f.y; d[2]=(bf16)f.z; d[3]=(bf16)f.w;
  } else if (b == 544) {               // global MLP
    if (tid < 128) zs[tid] = zg[tid];
    __syncthreads();
    float s = gb1[tid];
    for (int k = 0; k < 128; ++k) s += zs[k] * gw1[tid * 128 + k];
    ts[tid] = silu_f(s);
    __syncthreads();
    float s2 = gb2[tid];
    for (int k = 0; k < 256; ++k) s2 += ts[k] * gw2[tid * 256 + k];
    g[tid] = s2;
  } else {                             // bias512 = [dpb1, 0]
    bias512[tid] = dpb1[tid];
    bias512[256 + tid] = 0.f;
  }
}

// ---------------- generic MFMA GEMM: C = act(A @ W^T + bias) (+R) ----------------
template<int ACT, typename WT>
__global__ __launch_bounds__(256) void gemm_kernel(
    const float* __restrict__ A, int lda,
    const WT* __restrict__ W, int ldw,
    const float* __restrict__ bias,
    const float* __restrict__ R, int ldr,
    float* __restrict__ C, int ldc, int K)
{
  const int m0 = blockIdx.x * 64, n0 = blockIdx.y * 64;
  __shared__ bf16 As[64][72];
  __shared__ bf16 Ws[64][72];
  const int tid = threadIdx.x;
  const int lane = tid & 63, wid = tid >> 6;
  const int wm = (wid & 1) * 32, wn = (wid >> 1) * 32;
  const int rr = lane & 15, kg = (lane >> 4) << 3;
  f32x4 acc[2][2] = {};
  for (int k0 = 0; k0 < K; k0 += 64) {
#pragma unroll
    for (int r = 0; r < 4; ++r) {
      int lin = tid + r * 256;
      int row = lin >> 4, kc = (lin & 15) << 2;
      {
        const float* p = &A[(long)(m0 + row) * lda + k0 + kc];
        float4 v = *(const float4*)p;
        As[row][kc] = (bf16)v.x; As[row][kc + 1] = (bf16)v.y;
        As[row][kc + 2] = (bf16)v.z; As[row][kc + 3] = (bf16)v.w;
      }
      {
        const WT* p = &W[(long)(n0 + row) * ldw + k0 + kc];
        if constexpr (sizeof(WT) == 4) {
          float4 v = *(const float4*)p;
          Ws[row][kc] = (bf16)v.x; Ws[row][kc + 1] = (bf16)v.y;
          Ws[row][kc + 2] = (bf16)v.z; Ws[row][kc + 3] = (bf16)v.w;
        } else {
          *(uint2*)&Ws[row][kc] = *(const uint2*)p;
        }
      }
    }
    __syncthreads();
#pragma unroll
    for (int ks = 0; ks < 2; ++ks) {
      const int kk = ks * 32 + kg;
      bf16x8 a0 = *(const bf16x8*)&As[wm + rr][kk];
      bf16x8 a1 = *(const bf16x8*)&As[wm + 16 + rr][kk];
      bf16x8 b0 = *(const bf16x8*)&Ws[wn + rr][kk];
      bf16x8 b1 = *(const bf16x8*)&Ws[wn + 16 + rr][kk];
      acc[0][0] = __builtin_amdgcn_mfma_f32_16x16x32_bf16(a0, b0, acc[0][0], 0, 0, 0);
      acc[0][1] = __builtin_amdgcn_mfma_f32_16x16x32_bf16(a0, b1, acc[0][1], 0, 0, 0);
      acc[1][0] = __builtin_amdgcn_mfma_f32_16x16x32_bf16(a1, b0, acc[1][0], 0, 0, 0);
      acc[1][1] = __builtin_amdgcn_mfma_f32_16x16x32_bf16(a1, b1, acc[1][1], 0, 0, 0);
    }
    __syncthreads();
  }
  const int rg = lane >> 4;
#pragma unroll
  for (int mi = 0; mi < 2; ++mi)
#pragma unroll
    for (int ni = 0; ni < 2; ++ni)
#pragma unroll
      for (int r = 0; r < 4; ++r) {
        int gm = m0 + wm + mi * 16 + rg * 4 + r;
        int gn = n0 + wn + ni * 16 + rr;
        float v = acc[mi][ni][r];
        if (bias) v += bias[gn];
        if (R) v += R[(long)gm * ldr + gn];
        if (ACT == 1) v = silu_f(v);
        else if (ACT == 2) v = fmaxf(v, 0.f);
        C[(long)gm * ldc + gn] = v;
      }
}

// ---------------- fused attention (exact softmax, per layer) ----------------
__global__ __launch_bounds__(256) void attn_kernel(
    const float* __restrict__ qkv, float* __restrict__ o)
{
  __shared__ bf16 p_lds[4][8192];
  __shared__ bf16 vt_lds[8192];
  const int tid = threadIdx.x, lane = tid & 63, w = tid >> 6;
  const int l15 = lane & 15, kq = lane >> 4;
  const int q0 = blockIdx.x * 64, h = blockIdx.y;

  const float* qrow = qkv + (long)(q0 + w * 16 + l15) * 768 + h * 64 + kq * 8;
  bf16x8 qa[2];
#pragma unroll
  for (int ksq = 0; ksq < 2; ++ksq) {
    float4 f0 = *(const float4*)(qrow + ksq * 32);
    float4 f1 = *(const float4*)(qrow + ksq * 32 + 4);
    qa[ksq] = cvt8(f0, f1);
  }
  f32x4 accS[32];
#pragma unroll
  for (int nt = 0; nt < 32; ++nt) accS[nt] = (f32x4){0.f, 0.f, 0.f, 0.f};
#pragma unroll
  for (int nt = 0; nt < 32; ++nt) {
    const float* krow = qkv + (long)(nt * 16 + l15) * 768 + 256 + h * 64 + kq * 8;
    float4 a0 = *(const float4*)(krow);
    float4 a1 = *(const float4*)(krow + 4);
    float4 b0 = *(const float4*)(krow + 32);
    float4 b1 = *(const float4*)(krow + 36);
    bf16x8 kb0 = cvt8(a0, a1), kb1 = cvt8(b0, b1);
    accS[nt] = __builtin_amdgcn_mfma_f32_16x16x32_bf16(qa[0], kb0, accS[nt], 0, 0, 0);
    accS[nt] = __builtin_amdgcn_mfma_f32_16x16x32_bf16(qa[1], kb1, accS[nt], 0, 0, 0);
  }
#pragma unroll
  for (int r = 0; r < 4; ++r) {
    float mx = accS[0][r];
#pragma unroll
    for (int nt = 1; nt < 32; ++nt) mx = fmaxf(mx, accS[nt][r]);
    mx = fmaxf(mx, __shfl_xor(mx, 1)); mx = fmaxf(mx, __shfl_xor(mx, 2));
    mx = fmaxf(mx, __shfl_xor(mx, 4)); mx = fmaxf(mx, __shfl_xor(mx, 8));
    float s = 0.f;
#pragma unroll
    for (int nt = 0; nt < 32; ++nt) {
      float p = __expf((accS[nt][r] - mx) * 0.125f);
      accS[nt][r] = p; s += p;
    }
    s += __shfl_xor(s, 1); s += __shfl_xor(s, 2);
    s += __shfl_xor(s, 4); s += __shfl_xor(s, 8);
    float iv = fast_rcp(s);
#pragma unroll
    for (int nt = 0; nt < 32; ++nt) accS[nt][r] *= iv;
  }
  bf16* pw = &p_lds[w][0];
  const int ehi = l15 >> 3, elo = l15 & 7;
#pragma unroll
  for (int nt = 0; nt < 32; ++nt)
#pragma unroll
    for (int r = 0; r < 4; ++r)
      pw[((nt * 2 + ehi) * 16 + kq * 4 + r) * 8 + elo] = (bf16)accS[nt][r];

  f32x4 accO[4] = {};
  const int vd = tid & 63, kgrp = tid >> 6;
  for (int kc = 0; kc < 4; ++kc) {
    __syncthreads();
#pragma unroll
    for (int it = 0; it < 4; ++it) {
      int kkl = kgrp * 4 + it;
      const float* vp = qkv + (long)(kc * 128 + kkl * 8) * 768 + 512 + h * 64 + vd;
      bf16x8 vv;
#pragma unroll
      for (int e = 0; e < 8; ++e) vv[e] = (bf16)vp[e * 768];
      *(bf16x8*)&vt_lds[(kkl * 64 + vd) * 8] = vv;
    }
    __syncthreads();
#pragma unroll
    for (int ksq = 0; ksq < 4; ++ksq) {
      bf16x8 pa = *(const bf16x8*)&pw[((kc * 16 + ksq * 4 + kq) * 16 + l15) * 8];
#pragma unroll
      for (int ntd = 0; ntd < 4; ++ntd) {
        bf16x8 vb = *(const bf16x8*)&vt_lds[((ksq * 4 + kq) * 64 + ntd * 16 + l15) * 8];
        accO[ntd] = __builtin_amdgcn_mfma_f32_16x16x32_bf16(pa, vb, accO[ntd], 0, 0, 0);
      }
    }
  }
#pragma unroll
  for (int ntd = 0; ntd < 4; ++ntd)
#pragma unroll
    for (int r = 0; r < 4; ++r)
      o[(long)(q0 + w * 16 + kq * 4 + r) * 256 + h * 64 + ntd * 16 + l15] = accO[ntd][r];
}

// ---------------- LayerNorm rows of 256 ----------------
__global__ __launch_bounds__(256) void ln_kernel(
    const float* __restrict__ X, const float* __restrict__ sc,
    const float* __restrict__ bi, float* __restrict__ Y)
{
  int row = blockIdx.x, tid = threadIdx.x;
  float v = X[(long)row * 256 + tid];
  float s = v;
#pragma unroll
  for (int o = 1; o < 64; o <<= 1) s += __shfl_xor(s, o);
  __shared__ float r1[4];
  __shared__ float r2[4];
  if ((tid & 63) == 0) r1[tid >> 6] = s;
  __syncthreads();
  float mean = (r1[0] + r1[1] + r1[2] + r1[3]) * (1.f / 256.f);
  float d = v - mean;
  float t = d * d;
#pragma unroll
  for (int o = 1; o < 64; o <<= 1) t += __shfl_xor(t, o);
  if ((tid & 63) == 0) r2[tid >> 6] = t;
  __syncthreads();
  float var = (r2[0] + r2[1] + r2[2] + r2[3]) * (1.f / 256.f);
  Y[(long)row * 256 + tid] = d * rsqrtf(var + 1e-5f) * sc[tid] + bi[tid];
}

// ---------------- fused pair/dist kernel (fast silu, grid 1024, NO vgpr clamp) ----------------
// block = (i, half); 4 blocks/CU target: 128 VGPR + 34KB LDS.
__global__ __launch_bounds__(256, 2) void pair2_kernel(
    const float* __restrict__ ai, const float* __restrict__ aj,
    const bf16* __restrict__ W2P, const float* __restrict__ b2g,
    const float* __restrict__ w3g, const float* __restrict__ b3p,
    float* __restrict__ dout)
{
  __shared__ float ai_s[256];
  __shared__ bf16  t_s[64 * 256];     // (kk*64 + p)*8 + e
  __shared__ float part[64][4];
  const int tid = threadIdx.x, lane = tid & 63, w = tid >> 6;
  const int l15 = lane & 15, kq = lane >> 4;
  const int i = blockIdx.x >> 1, half = blockIdx.x & 1;
  const float b3v = b3p[0];

  ai_s[tid] = ai[(long)i * 512 + tid];

  bf16x8 w2r[4][8];
  float b2v[4], w3v[4];
#pragma unroll
  for (int nt = 0; nt < 4; ++nt) {
    int ntg = w * 4 + nt;
#pragma unroll
    for (int ks = 0; ks < 8; ++ks)
      w2r[nt][ks] = *(const bf16x8*)&W2P[(long)((((ntg * 8 + ks) * 4 + kq) * 16) + l15) * 8];
    b2v[nt] = b2g[ntg * 16 + l15];
    w3v[nt] = w3g[ntg * 16 + l15];
  }
  __syncthreads();

  for (int jc = half * 4; jc < half * 4 + 4; ++jc) {
    const int j0 = jc * 64;
    const float* ajp = aj + (long)(j0 + lane) * 512;
#pragma unroll
    for (int r = 0; r < 8; ++r) {
      int kk = w + 4 * r;
      float4 a0 = *(const float4*)(ajp + kk * 8);
      float4 a1 = *(const float4*)(ajp + kk * 8 + 4);
      const float* aip = ai_s + kk * 8;
      bf16x8 tv;
      tv[0] = (bf16)silu_f(a0.x + aip[0]); tv[1] = (bf16)silu_f(a0.y + aip[1]);
      tv[2] = (bf16)silu_f(a0.z + aip[2]); tv[3] = (bf16)silu_f(a0.w + aip[3]);
      tv[4] = (bf16)silu_f(a1.x + aip[4]); tv[5] = (bf16)silu_f(a1.y + aip[5]);
      tv[6] = (bf16)silu_f(a1.z + aip[6]); tv[7] = (bf16)silu_f(a1.w + aip[7]);
      *(bf16x8*)&t_s[(kk * 64 + lane) * 8] = tv;
    }
    __syncthreads();   // t ready

    f32x4 acc[4][4] = {};
#pragma unroll
    for (int ks = 0; ks < 8; ++ks) {
      bf16x8 af[4];
#pragma unroll
      for (int Mt = 0; Mt < 4; ++Mt)
        af[Mt] = *(const bf16x8*)&t_s[((ks * 4 + kq) * 64 + Mt * 16 + l15) * 8];
#pragma unroll
      for (int nt = 0; nt < 4; ++nt)
#pragma unroll
        for (int Mt = 0; Mt < 4; ++Mt)
          acc[Mt][nt] = __builtin_amdgcn_mfma_f32_16x16x32_bf16(af[Mt], w2r[nt][ks], acc[Mt][nt], 0, 0, 0);
    }

#pragma unroll
    for (int Mt = 0; Mt < 4; ++Mt)
#pragma unroll
      for (int r = 0; r < 4; ++r) {
        float s = silu_f(acc[Mt][0][r] + b2v[0]) * w3v[0]
                + silu_f(acc[Mt][1][r] + b2v[1]) * w3v[1]
                + silu_f(acc[Mt][2][r] + b2v[2]) * w3v[2]
                + silu_f(acc[Mt][3][r] + b2v[3]) * w3v[3];
        s += __shfl_xor(s, 1); s += __shfl_xor(s, 2);
        s += __shfl_xor(s, 4); s += __shfl_xor(s, 8);
        if (l15 == 0) part[Mt * 16 + kq * 4 + r][w] = s;
      }
    __syncthreads();   // part ready
    if (tid < 64) {
      float s = part[tid][0] + part[tid][1] + part[tid][2] + part[tid][3] + b3v;
      float dd = fmaxf(s, 0.f) + log1pf(__expf(-fabsf(s)));
      dout[(long)i * 512 + j0 + tid] = dd;
    }
    __syncthreads();   // reuse t_s / part next iter
  }
}

// ---------------- symmetrize dist in place ----------------
__global__ __launch_bounds__(256) void sym_kernel(float* __restrict__ dist)
{
  int idx = blockIdx.x * 256 + threadIdx.x;
  int i = idx >> 9, j = idx & 511;
  if (i < j) {
    float a = dist[idx];
    float b = dist[(long)j * 512 + i];
    float m = 0.5f * (a + b);
    dist[idx] = m;
    dist[(long)j * 512 + i] = m;
  }
}

// ---------------- coordinate head final 256->3 ----------------
__global__ __launch_bounds__(256) void coord_kernel(
    const float* __restrict__ ct, const float* __restrict__ w2,
    const float* __restrict__ b2, float* __restrict__ out)
{
  int t = blockIdx.x * 256 + threadIdx.x;
  if (t >= 1536) return;
  int row = t / 3, c = t - row * 3;
  float s = b2[c];
  const float* a = &ct[(long)row * 256];
  const float* wp = &w2[c * 256];
  for (int k = 0; k < 256; ++k) s += a[k] * wp[k];
  out[t] = s;
}

extern "C" void kernel_launch(void* const* d_in, const int* in_sizes, int n_in,
                              void* d_out, int out_size, void* d_ws, size_t ws_size,
                              hipStream_t stream) {
  const float* z        = (const float*)d_in[0];
  const float* z_global = (const float*)d_in[1];
  const int*   atom_t   = (const int*)d_in[2];
  const float* emb      = (const float*)d_in[3];
  const float* ip_w1 = (const float*)d_in[4];  const float* ip_b1 = (const float*)d_in[5];
  const float* ip_w2 = (const float*)d_in[6];  const float* ip_b2 = (const float*)d_in[7];
  const float* gp_w1 = (const float*)d_in[8];  const float* gp_b1 = (const float*)d_in[9];
  const float* gp_w2 = (const float*)d_in[10]; const float* gp_b2 = (const float*)d_in[11];
  const float* wqkv  = (const float*)d_in[12]; const float* bqkv  = (const float*)d_in[13];
  const float* wo    = (const float*)d_in[14]; const float* bo    = (const float*)d_in[15];
  const float* ln1s  = (const float*)d_in[16]; const float* ln1b  = (const float*)d_in[17];
  const float* w1    = (const float*)d_in[18]; const float* b1    = (const float*)d_in[19];
  const float* w2    = (const float*)d_in[20]; const float* b2    = (const float*)d_in[21];
  const float* ln2s  = (const float*)d_in[22]; const float* ln2b  = (const float*)d_in[23];
  const float* dpw1  = (const float*)d_in[24]; const float* dpb1  = (const float*)d_in[25];
  const float* dpw2  = (const float*)d_in[26]; const float* dpb2  = (const float*)d_in[27];
  const float* dpw3  = (const float*)d_in[28]; const float* dpb3  = (const float*)d_in[29];
  const float* cpw1  = (const float*)d_in[30]; const float* cpb1  = (const float*)d_in[31];
  const float* cpw2  = (const float*)d_in[32]; const float* cpb2  = (const float*)d_in[33];

  char* ws = (char*)d_ws;
  bf16*  W2P  = (bf16*)(ws + O_W2P);
  bf16*  WDP  = (bf16*)(ws + O_WDP);
  float* b512 = (float*)(ws + O_B512);
  float* zin  = (float*)(ws + F_ZIN);
  float* g    = (float*)(ws + F_G);
  float* h    = (float*)(ws + F_H);
  float* qkv  = (float*)(ws + F_QKV);
  float* ff1  = (float*)(ws + F_FF1);
  float* o    = (float*)(ws + F_O);
  float* t1   = (float*)(ws + F_T1);
  float* aiaj = (float*)(ws + F_AIAJ);
  float* out  = (float*)d_out;
  float* xout = out;
  float* dist = out + 1536;

  prep_kernel<<<546, 256, 0, stream>>>(z, atom_t, emb, dpw2, dpw1,
      z_global, gp_w1, gp_b1, gp_w2, gp_b2, dpb1, zin, W2P, WDP, g, b512);

  gemm_kernel<1, float><<<dim3(8, 4), 256, 0, stream>>>(zin, 192, ip_w1, 192,
      ip_b1, nullptr, 0, t1, 256, 192);
  gemm_kernel<0, float><<<dim3(8, 4), 256, 0, stream>>>(t1, 256, ip_w2, 256,
      ip_b2, g, 0, h, 256, 256);

  for (int l = 0; l < 3; ++l) {
    gemm_kernel<0, float><<<dim3(8, 12), 256, 0, stream>>>(h, 256,
        wqkv + (long)l * 768 * 256, 256, bqkv + l * 768, nullptr, 0, qkv, 768, 256);
    attn_kernel<<<dim3(8, 4), 256, 0, stream>>>(qkv, o);
    gemm_kernel<0, float><<<dim3(8, 4), 256, 0, stream>>>(o, 256,
        wo + (long)l * 65536, 256, bo + l * 256, h, 256, t1, 256, 256);
    ln_kernel<<<512, 256, 0, stream>>>(t1, ln1s + l * 256, ln1b + l * 256, h);
    gemm_kernel<2, float><<<dim3(8, 16), 256, 0, stream>>>(h, 256,
        w1 + (long)l * 262144, 256, b1 + l * 1024, nullptr, 0, ff1, 1024, 256);
    gemm_kernel<0, float><<<dim3(8, 4), 256, 0, stream>>>(ff1, 1024,
        w2 + (long)l * 262144, 1024, b2 + l * 256, h, 256, t1, 256, 1024);
    ln_kernel<<<512, 256, 0, stream>>>(t1, ln2s + l * 256, ln2b + l * 256, h);
  }

  // [ai | aj] = h @ [dpw1_lo ; dpw1_hi]^T + [b1 | 0]
  gemm_kernel<0, bf16><<<dim3(8, 8), 256, 0, stream>>>(h, 256, WDP, 256,
      b512, nullptr, 0, aiaj, 512, 256);
  pair2_kernel<<<1024, 256, 0, stream>>>(aiaj, aiaj + 256, W2P, dpb2, dpw3, dpb3, dist);
  sym_kernel<<<1024, 256, 0, stream>>>(dist);
  gemm_kernel<1, float><<<dim3(8, 4), 256, 0, stream>>>(h, 256, cpw1, 256,
      cpb1, nullptr, 0, t1, 256, 256);
  coord_kernel<<<6, 256, 0, stream>>>(t1, cpw2, cpb2, xout);
}

// Round 5
// 375.169 us; speedup vs baseline: 1.6245x; 1.4032x over previous
//
#include <hip/hip_runtime.h>
#include <hip/hip_bf16.h>
#include <cstdint>

typedef __bf16 bf16;
typedef __attribute__((ext_vector_type(8))) __bf16 bf16x8;
typedef __attribute__((ext_vector_type(4))) float f32x4;

__device__ __forceinline__ float fast_rcp(float x) { return __builtin_amdgcn_rcpf(x); }
__device__ __forceinline__ float silu_f(float x) { return x * fast_rcp(1.f + __expf(-x)); }
__device__ __forceinline__ bf16x8 cvt8(float4 a, float4 b) {
  bf16x8 o;
  o[0]=(bf16)a.x; o[1]=(bf16)a.y; o[2]=(bf16)a.z; o[3]=(bf16)a.w;
  o[4]=(bf16)b.x; o[5]=(bf16)b.y; o[6]=(bf16)b.z; o[7]=(bf16)b.w;
  return o;
}

// ---------------- ws layout ----------------
// bf16 weight arena (element offsets into (bf16*)ws) — round-2 proven
constexpr long WB_IPW1 = 0;          // 256*192
constexpr long WB_IPW2 = 49152;      // 256*256
constexpr long WB_QKV  = 114688;     // 3*768*256
constexpr long WB_WO   = 704512;     // 3*256*256
constexpr long WB_W1   = 901120;     // 3*1024*256
constexpr long WB_W2   = 1687552;    // 3*256*1024
constexpr long WB_DPW1 = 2473984;    // 256*512 (converted, unused — kept for convw verbatim)
constexpr long WB_DPW2 = 2605056;    // 256*256 (converted, unused)
constexpr long WB_CPW1 = 2670592;    // 256*256
// float buffers (byte offsets) — round-2 proven
constexpr long F_ZIN = 5472256;                 // 512*192 f32
constexpr long F_G   = F_ZIN + 512L*192*4;      // 256 f32
constexpr long F_H   = F_G + 1024;              // 512*256 f32
constexpr long F_QKV = F_H + 512L*256*4;        // 512*768 f32
constexpr long F_S   = F_QKV + 512L*768*4;      // 4*512*512 f32 (S / ff1 / later aiaj)
constexpr long F_VT  = F_S + 4L*512*512*4;      // 4*64*512 bf16
constexpr long F_O   = F_VT + 4L*64*512*2;      // 512*256 f32
constexpr long F_T1  = F_O + 512L*256*4;        // 512*256 f32
constexpr long O_W2P  = F_T1 + 512L*256*4;      // 8192*8 bf16 = 131072 B
constexpr long O_WDP  = O_W2P + 131072;         // 512*256 bf16 = 262144 B
constexpr long O_B512 = O_WDP + 262144;         // 512 f32

// ---------------- prep: convw + zin + W2P perm + WDP pack + gproj + bias512 ----------------
__global__ __launch_bounds__(256) void prep_kernel(
    const float* __restrict__ s_ipw1, const float* __restrict__ s_ipw2,
    const float* __restrict__ s_qkv,  const float* __restrict__ s_wo,
    const float* __restrict__ s_w1,   const float* __restrict__ s_w2,
    const float* __restrict__ s_dpw1, const float* __restrict__ s_dpw2,
    const float* __restrict__ s_cpw1, bf16* __restrict__ dst,
    const float* __restrict__ z, const int* __restrict__ at, const float* __restrict__ emb,
    const float* __restrict__ zg, const float* __restrict__ gw1, const float* __restrict__ gb1,
    const float* __restrict__ gw2, const float* __restrict__ gb2,
    const float* __restrict__ dpb1,
    float* __restrict__ zi, bf16* __restrict__ w2p, bf16* __restrict__ wdp,
    float* __restrict__ g, float* __restrict__ bias512)
{
  __shared__ float zs[128];
  __shared__ float ts[256];
  const int b = blockIdx.x, tid = threadIdx.x;
  if (b < 2672) {                      // weight fp32 -> bf16 arena (round-1 verbatim)
    long v = (long)b * 256 + tid;
    if (v >= 684032) return;
    const float* src; long off;
    if (v < 176128) {
      if (v < 12288)      { src = s_ipw1; off = 0; }
      else if (v < 28672) { src = s_ipw2; off = 12288; }
      else                { src = s_qkv;  off = 28672; }
    } else if (v < 618496) {
      if (v < 225280)      { src = s_wo; off = 176128; }
      else if (v < 421888) { src = s_w1; off = 225280; }
      else                 { src = s_w2; off = 421888; }
    } else {
      if (v < 651264)      { src = s_dpw1; off = 618496; }
      else if (v < 667648) { src = s_dpw2; off = 651264; }
      else                 { src = s_cpw1; off = 667648; }
    }
    long e = (v - off) * 4;
    float4 f = *(const float4*)&src[e];
    bf16* d = dst + off * 4 + e;
    d[0] = (bf16)f.x; d[1] = (bf16)f.y; d[2] = (bf16)f.z; d[3] = (bf16)f.w;
  } else if (b < 3056) {               // z_input concat
    int idx = (b - 2672) * 256 + tid;
    int n = idx / 192, c = idx - n * 192;
    zi[idx] = (c < 128) ? z[n * 128 + c] : emb[at[n] * 64 + (c - 128)];
  } else if (b < 3088) {               // W2 -> B-frag-linear bf16 (round-4 verbatim)
    int f = (b - 3056) * 256 + tid;    // 8192 frags
    int l15 = f & 15, kq = (f >> 4) & 3, ks = (f >> 6) & 7, nt = f >> 9;
    int n = nt * 16 + l15, k0 = ks * 32 + kq * 8;
    float4 v0 = *(const float4*)&s_dpw2[n * 256 + k0];
    float4 v1 = *(const float4*)&s_dpw2[n * 256 + k0 + 4];
    *(bf16x8*)&w2p[(long)f * 8] = cvt8(v0, v1);
  } else if (b < 3216) {               // stacked dp_w1 (512x256) bf16 (round-4 verbatim)
    int v = (b - 3088) * 256 + tid;    // 32768 vec4
    int r = v >> 6, c4 = (v & 63) << 2;
    long src = (r < 256) ? ((long)r * 512 + c4) : ((long)(r - 256) * 512 + 256 + c4);
    float4 f = *(const float4*)&s_dpw1[src];
    bf16* d = &wdp[r * 256 + c4];
    d[0]=(bf16)f.x; d[1]=(bf16)f.y; d[2]=(bf16)f.z; d[3]=(bf16)f.w;
  } else if (b == 3216) {              // global MLP
    if (tid < 128) zs[tid] = zg[tid];
    __syncthreads();
    float s = gb1[tid];
    for (int k = 0; k < 128; ++k) s += zs[k] * gw1[tid * 128 + k];
    ts[tid] = silu_f(s);
    __syncthreads();
    float s2 = gb2[tid];
    for (int k = 0; k < 256; ++k) s2 += ts[k] * gw2[tid * 256 + k];
    g[tid] = s2;
  } else {                             // bias512 = [dpb1, 0]
    bias512[tid] = dpb1[tid];
    bias512[256 + tid] = 0.f;
  }
}

// ---------------- generic MFMA GEMM: C = act(A @ W^T + bias) (+R) — round-2 verbatim ----------------
template<int ACT, typename WT>
__global__ __launch_bounds__(256) void gemm_kernel(
    const float* __restrict__ A, int lda, long sA,
    const WT* __restrict__ W, int ldw, long sW,
    const float* __restrict__ bias,
    const float* __restrict__ R, int ldr, long sR,
    float* __restrict__ C, int ldc, long sC, int K)
{
  const int bz = blockIdx.z;
  A += (long)bz * sA;  W += (long)bz * sW;  C += (long)bz * sC;
  if (R) R += (long)bz * sR;
  const int m0 = blockIdx.x * 64, n0 = blockIdx.y * 64;
  __shared__ bf16 As[64][72];
  __shared__ bf16 Ws[64][72];
  const int tid = threadIdx.x;
  const int lane = tid & 63, wid = tid >> 6;
  const int wm = (wid & 1) * 32, wn = (wid >> 1) * 32;
  const int rr = lane & 15, kg = (lane >> 4) << 3;
  f32x4 acc[2][2] = {};
  for (int k0 = 0; k0 < K; k0 += 64) {
#pragma unroll
    for (int r = 0; r < 4; ++r) {
      int lin = tid + r * 256;
      int row = lin >> 4, kc = (lin & 15) << 2;
      {
        const float* p = &A[(long)(m0 + row) * lda + k0 + kc];
        float4 v = *(const float4*)p;
        As[row][kc] = (bf16)v.x; As[row][kc + 1] = (bf16)v.y;
        As[row][kc + 2] = (bf16)v.z; As[row][kc + 3] = (bf16)v.w;
      }
      {
        const WT* p = &W[(long)(n0 + row) * ldw + k0 + kc];
        if constexpr (sizeof(WT) == 4) {
          float4 v = *(const float4*)p;
          Ws[row][kc] = (bf16)v.x; Ws[row][kc + 1] = (bf16)v.y;
          Ws[row][kc + 2] = (bf16)v.z; Ws[row][kc + 3] = (bf16)v.w;
        } else {
          *(uint2*)&Ws[row][kc] = *(const uint2*)p;
        }
      }
    }
    __syncthreads();
#pragma unroll
    for (int ks = 0; ks < 2; ++ks) {
      const int kk = ks * 32 + kg;
      bf16x8 a0 = *(const bf16x8*)&As[wm + rr][kk];
      bf16x8 a1 = *(const bf16x8*)&As[wm + 16 + rr][kk];
      bf16x8 b0 = *(const bf16x8*)&Ws[wn + rr][kk];
      bf16x8 b1 = *(const bf16x8*)&Ws[wn + 16 + rr][kk];
      acc[0][0] = __builtin_amdgcn_mfma_f32_16x16x32_bf16(a0, b0, acc[0][0], 0, 0, 0);
      acc[0][1] = __builtin_amdgcn_mfma_f32_16x16x32_bf16(a0, b1, acc[0][1], 0, 0, 0);
      acc[1][0] = __builtin_amdgcn_mfma_f32_16x16x32_bf16(a1, b0, acc[1][0], 0, 0, 0);
      acc[1][1] = __builtin_amdgcn_mfma_f32_16x16x32_bf16(a1, b1, acc[1][1], 0, 0, 0);
    }
    __syncthreads();
  }
  const int rg = lane >> 4;
#pragma unroll
  for (int mi = 0; mi < 2; ++mi)
#pragma unroll
    for (int ni = 0; ni < 2; ++ni)
#pragma unroll
      for (int r = 0; r < 4; ++r) {
        int gm = m0 + wm + mi * 16 + rg * 4 + r;
        int gn = n0 + wn + ni * 16 + rr;
        float v = acc[mi][ni][r];
        if (bias) v += bias[gn];
        if (R) v += R[(long)gm * ldr + gn];
        if (ACT == 1) v = silu_f(v);
        else if (ACT == 2) v = fmaxf(v, 0.f);
        C[(long)gm * ldc + gn] = v;
      }
}

// ---------------- row softmax over S (4,512,512), scale=1/8 — round-2 verbatim ----------------
__global__ __launch_bounds__(256) void softmax_kernel(float* __restrict__ S)
{
  long base = ((long)blockIdx.y * 512 + blockIdx.x) * 512;
  float* row = S + base;
  int tid = threadIdx.x;
  float a = row[tid] * 0.125f, b = row[tid + 256] * 0.125f;
  float m = fmaxf(a, b);
#pragma unroll
  for (int o = 1; o < 64; o <<= 1) m = fmaxf(m, __shfl_xor(m, o));
  __shared__ float red[4];
  __shared__ float red2[4];
  int wid = tid >> 6;
  if ((tid & 63) == 0) red[wid] = m;
  __syncthreads();
  m = fmaxf(fmaxf(red[0], red[1]), fmaxf(red[2], red[3]));
  float e0 = __expf(a - m), e1 = __expf(b - m);
  float s = e0 + e1;
#pragma unroll
  for (int o = 1; o < 64; o <<= 1) s += __shfl_xor(s, o);
  if ((tid & 63) == 0) red2[wid] = s;
  __syncthreads();
  s = red2[0] + red2[1] + red2[2] + red2[3];
  float inv = fast_rcp(s);
  row[tid] = e0 * inv; row[tid + 256] = e1 * inv;
}

// ---------------- V transpose -> Vt[h][d][n] (bf16) — round-2 verbatim ----------------
__global__ __launch_bounds__(256) void vt_kernel(const float* __restrict__ qkv, bf16* __restrict__ vt)
{
  int idx = blockIdx.x * 256 + threadIdx.x;   // < 131072
  int hh = idx >> 15;
  int r = idx & 32767;
  int d = r >> 9, n = r & 511;
  vt[idx] = (bf16)qkv[(long)n * 768 + 512 + hh * 64 + d];
}

// ---------------- LayerNorm rows of 256 — round-2 verbatim ----------------
__global__ __launch_bounds__(256) void ln_kernel(
    const float* __restrict__ X, const float* __restrict__ sc,
    const float* __restrict__ bi, float* __restrict__ Y)
{
  int row = blockIdx.x, tid = threadIdx.x;
  float v = X[(long)row * 256 + tid];
  float s = v;
#pragma unroll
  for (int o = 1; o < 64; o <<= 1) s += __shfl_xor(s, o);
  __shared__ float r1[4];
  __shared__ float r2[4];
  if ((tid & 63) == 0) r1[tid >> 6] = s;
  __syncthreads();
  float mean = (r1[0] + r1[1] + r1[2] + r1[3]) * (1.f / 256.f);
  float d = v - mean;
  float t = d * d;
#pragma unroll
  for (int o = 1; o < 64; o <<= 1) t += __shfl_xor(t, o);
  if ((tid & 63) == 0) r2[tid >> 6] = t;
  __syncthreads();
  float var = (r2[0] + r2[1] + r2[2] + r2[3]) * (1.f / 256.f);
  Y[(long)row * 256 + tid] = d * rsqrtf(var + 1e-5f) * sc[tid] + bi[tid];
}

// ---------------- fused pair/dist kernel — round-4 verbatim (99 µs validated) ----------------
__global__ __launch_bounds__(256, 2) void pair2_kernel(
    const float* __restrict__ ai, const float* __restrict__ aj,
    const bf16* __restrict__ W2P, const float* __restrict__ b2g,
    const float* __restrict__ w3g, const float* __restrict__ b3p,
    float* __restrict__ dout)
{
  __shared__ float ai_s[256];
  __shared__ bf16  t_s[64 * 256];
  __shared__ float part[64][4];
  const int tid = threadIdx.x, lane = tid & 63, w = tid >> 6;
  const int l15 = lane & 15, kq = lane >> 4;
  const int i = blockIdx.x >> 1, half = blockIdx.x & 1;
  const float b3v = b3p[0];

  ai_s[tid] = ai[(long)i * 512 + tid];

  bf16x8 w2r[4][8];
  float b2v[4], w3v[4];
#pragma unroll
  for (int nt = 0; nt < 4; ++nt) {
    int ntg = w * 4 + nt;
#pragma unroll
    for (int ks = 0; ks < 8; ++ks)
      w2r[nt][ks] = *(const bf16x8*)&W2P[(long)((((ntg * 8 + ks) * 4 + kq) * 16) + l15) * 8];
    b2v[nt] = b2g[ntg * 16 + l15];
    w3v[nt] = w3g[ntg * 16 + l15];
  }
  __syncthreads();

  for (int jc = half * 4; jc < half * 4 + 4; ++jc) {
    const int j0 = jc * 64;
    const float* ajp = aj + (long)(j0 + lane) * 512;
#pragma unroll
    for (int r = 0; r < 8; ++r) {
      int kk = w + 4 * r;
      float4 a0 = *(const float4*)(ajp + kk * 8);
      float4 a1 = *(const float4*)(ajp + kk * 8 + 4);
      const float* aip = ai_s + kk * 8;
      bf16x8 tv;
      tv[0] = (bf16)silu_f(a0.x + aip[0]); tv[1] = (bf16)silu_f(a0.y + aip[1]);
      tv[2] = (bf16)silu_f(a0.z + aip[2]); tv[3] = (bf16)silu_f(a0.w + aip[3]);
      tv[4] = (bf16)silu_f(a1.x + aip[4]); tv[5] = (bf16)silu_f(a1.y + aip[5]);
      tv[6] = (bf16)silu_f(a1.z + aip[6]); tv[7] = (bf16)silu_f(a1.w + aip[7]);
      *(bf16x8*)&t_s[(kk * 64 + lane) * 8] = tv;
    }
    __syncthreads();

    f32x4 acc[4][4] = {};
#pragma unroll
    for (int ks = 0; ks < 8; ++ks) {
      bf16x8 af[4];
#pragma unroll
      for (int Mt = 0; Mt < 4; ++Mt)
        af[Mt] = *(const bf16x8*)&t_s[((ks * 4 + kq) * 64 + Mt * 16 + l15) * 8];
#pragma unroll
      for (int nt = 0; nt < 4; ++nt)
#pragma unroll
        for (int Mt = 0; Mt < 4; ++Mt)
          acc[Mt][nt] = __builtin_amdgcn_mfma_f32_16x16x32_bf16(af[Mt], w2r[nt][ks], acc[Mt][nt], 0, 0, 0);
    }

#pragma unroll
    for (int Mt = 0; Mt < 4; ++Mt)
#pragma unroll
      for (int r = 0; r < 4; ++r) {
        float s = silu_f(acc[Mt][0][r] + b2v[0]) * w3v[0]
                + silu_f(acc[Mt][1][r] + b2v[1]) * w3v[1]
                + silu_f(acc[Mt][2][r] + b2v[2]) * w3v[2]
                + silu_f(acc[Mt][3][r] + b2v[3]) * w3v[3];
        s += __shfl_xor(s, 1); s += __shfl_xor(s, 2);
        s += __shfl_xor(s, 4); s += __shfl_xor(s, 8);
        if (l15 == 0) part[Mt * 16 + kq * 4 + r][w] = s;
      }
    __syncthreads();
    if (tid < 64) {
      float s = part[tid][0] + part[tid][1] + part[tid][2] + part[tid][3] + b3v;
      float dd = fmaxf(s, 0.f) + log1pf(__expf(-fabsf(s)));
      dout[(long)i * 512 + j0 + tid] = dd;
    }
    __syncthreads();
  }
}

// ---------------- symmetrize dist in place ----------------
__global__ __launch_bounds__(256) void sym_kernel(float* __restrict__ dist)
{
  int idx = blockIdx.x * 256 + threadIdx.x;
  int i = idx >> 9, j = idx & 511;
  if (i < j) {
    float a = dist[idx];
    float b = dist[(long)j * 512 + i];
    float m = 0.5f * (a + b);
    dist[idx] = m;
    dist[(long)j * 512 + i] = m;
  }
}

// ---------------- coordinate head final 256->3 ----------------
__global__ __launch_bounds__(256) void coord_kernel(
    const float* __restrict__ ct, const float* __restrict__ w2,
    const float* __restrict__ b2, float* __restrict__ out)
{
  int t = blockIdx.x * 256 + threadIdx.x;
  if (t >= 1536) return;
  int row = t / 3, c = t - row * 3;
  float s = b2[c];
  const float* a = &ct[(long)row * 256];
  const float* wp = &w2[c * 256];
  for (int k = 0; k < 256; ++k) s += a[k] * wp[k];
  out[t] = s;
}

extern "C" void kernel_launch(void* const* d_in, const int* in_sizes, int n_in,
                              void* d_out, int out_size, void* d_ws, size_t ws_size,
                              hipStream_t stream) {
  const float* z        = (const float*)d_in[0];
  const float* z_global = (const float*)d_in[1];
  const int*   atom_t   = (const int*)d_in[2];
  const float* emb      = (const float*)d_in[3];
  const float* ip_w1 = (const float*)d_in[4];  const float* ip_b1 = (const float*)d_in[5];
  const float* ip_w2 = (const float*)d_in[6];  const float* ip_b2 = (const float*)d_in[7];
  const float* gp_w1 = (const float*)d_in[8];  const float* gp_b1 = (const float*)d_in[9];
  const float* gp_w2 = (const float*)d_in[10]; const float* gp_b2 = (const float*)d_in[11];
  const float* wqkv  = (const float*)d_in[12]; const float* bqkv  = (const float*)d_in[13];
  const float* wo    = (const float*)d_in[14]; const float* bo    = (const float*)d_in[15];
  const float* ln1s  = (const float*)d_in[16]; const float* ln1b  = (const float*)d_in[17];
  const float* w1    = (const float*)d_in[18]; const float* b1    = (const float*)d_in[19];
  const float* w2    = (const float*)d_in[20]; const float* b2    = (const float*)d_in[21];
  const float* ln2s  = (const float*)d_in[22]; const float* ln2b  = (const float*)d_in[23];
  const float* dpw1  = (const float*)d_in[24]; const float* dpb1  = (const float*)d_in[25];
  const float* dpw2  = (const float*)d_in[26]; const float* dpb2  = (const float*)d_in[27];
  const float* dpw3  = (const float*)d_in[28]; const float* dpb3  = (const float*)d_in[29];
  const float* cpw1  = (const float*)d_in[30]; const float* cpb1  = (const float*)d_in[31];
  const float* cpw2  = (const float*)d_in[32]; const float* cpb2  = (const float*)d_in[33];

  char* ws = (char*)d_ws;
  bf16*  WB   = (bf16*)ws;
  float* zin  = (float*)(ws + F_ZIN);
  float* g    = (float*)(ws + F_G);
  float* h    = (float*)(ws + F_H);
  float* qkv  = (float*)(ws + F_QKV);
  float* S    = (float*)(ws + F_S);
  bf16*  Vt   = (bf16*)(ws + F_VT);
  float* o    = (float*)(ws + F_O);
  float* t1   = (float*)(ws + F_T1);
  bf16*  W2P  = (bf16*)(ws + O_W2P);
  bf16*  WDP  = (bf16*)(ws + O_WDP);
  float* b512 = (float*)(ws + O_B512);
  float* ff1  = S;                   // reuse during transformer
  float* aiaj = S;                   // reuse after transformer (1MB < 4MB)
  float* out  = (float*)d_out;
  float* xout = out;
  float* dist = out + 1536;

  prep_kernel<<<3218, 256, 0, stream>>>(ip_w1, ip_w2, wqkv, wo, w1, w2, dpw1, dpw2, cpw1, WB,
      z, atom_t, emb, z_global, gp_w1, gp_b1, gp_w2, gp_b2, dpb1,
      zin, W2P, WDP, g, b512);

  gemm_kernel<1, bf16><<<dim3(8, 4, 1), 256, 0, stream>>>(zin, 192, 0, WB + WB_IPW1, 192, 0,
      ip_b1, nullptr, 0, 0, t1, 256, 0, 192);
  gemm_kernel<0, bf16><<<dim3(8, 4, 1), 256, 0, stream>>>(t1, 256, 0, WB + WB_IPW2, 256, 0,
      ip_b2, g, 0, 0, h, 256, 0, 256);

  for (int l = 0; l < 3; ++l) {
    const bf16* wq = WB + WB_QKV + (long)l * 768 * 256;
    gemm_kernel<0, bf16><<<dim3(8, 12, 1), 256, 0, stream>>>(h, 256, 0, wq, 256, 0,
        bqkv + l * 768, nullptr, 0, 0, qkv, 768, 0, 256);
    gemm_kernel<0, float><<<dim3(8, 8, 4), 256, 0, stream>>>(qkv, 768, 64, qkv + 256, 768, 64,
        nullptr, nullptr, 0, 0, S, 512, 262144, 64);
    softmax_kernel<<<dim3(512, 4), 256, 0, stream>>>(S);
    vt_kernel<<<512, 256, 0, stream>>>(qkv, Vt);
    gemm_kernel<0, bf16><<<dim3(8, 1, 4), 256, 0, stream>>>(S, 512, 262144, Vt, 512, 32768,
        nullptr, nullptr, 0, 0, o, 256, 64, 512);
    gemm_kernel<0, bf16><<<dim3(8, 4, 1), 256, 0, stream>>>(o, 256, 0,
        WB + WB_WO + (long)l * 65536, 256, 0, bo + l * 256, h, 256, 0, t1, 256, 0, 256);
    ln_kernel<<<512, 256, 0, stream>>>(t1, ln1s + l * 256, ln1b + l * 256, h);
    gemm_kernel<2, bf16><<<dim3(8, 16, 1), 256, 0, stream>>>(h, 256, 0,
        WB + WB_W1 + (long)l * 262144, 256, 0, b1 + l * 1024, nullptr, 0, 0, ff1, 1024, 0, 256);
    gemm_kernel<0, bf16><<<dim3(8, 4, 1), 256, 0, stream>>>(ff1, 1024, 0,
        WB + WB_W2 + (long)l * 262144, 1024, 0, b2 + l * 256, h, 256, 0, t1, 256, 0, 1024);
    ln_kernel<<<512, 256, 0, stream>>>(t1, ln2s + l * 256, ln2b + l * 256, h);
  }

  // [ai | aj] = h @ [dpw1_lo ; dpw1_hi]^T + [b1 | 0]  (aiaj overlays dead S/ff1)
  gemm_kernel<0, bf16><<<dim3(8, 8, 1), 256, 0, stream>>>(h, 256, 0, WDP, 256, 0,
      b512, nullptr, 0, 0, aiaj, 512, 0, 256);
  pair2_kernel<<<1024, 256, 0, stream>>>(aiaj, aiaj + 256, W2P, dpb2, dpw3, dpb3, dist);
  sym_kernel<<<1024, 256, 0, stream>>>(dist);
  gemm_kernel<1, bf16><<<dim3(8, 4, 1), 256, 0, stream>>>(h, 256, 0, WB + WB_CPW1, 256, 0,
      cpb1, nullptr, 0, 0, t1, 256, 0, 256);
  coord_kernel<<<6, 256, 0, stream>>>(t1, cpw2, cpb2, xout);
}